// Round 2
// baseline (965.933 us; speedup 1.0000x reference)
//
#include <hip/hip_runtime.h>
#include <cstdint>

// Problem constants
#define Bq   2
#define Tq   2048
#define Dq   2048
#define Hq   16
#define DKq  64
#define DVq  128
#define Cq   64          // chunk len
#define NCq  32          // chunks
#define Mq   4096        // B*T
#define NBH  32          // B*H

typedef __bf16 bf16;
typedef __bf16 bf16x4 __attribute__((ext_vector_type(4)));
typedef __bf16 bf16x8 __attribute__((ext_vector_type(8)));
typedef float  f32x4  __attribute__((ext_vector_type(4)));

__device__ __forceinline__ void gl_lds16(const bf16* g, bf16* l) {
    __builtin_amdgcn_global_load_lds(
        (const __attribute__((address_space(1))) uint32_t*)g,
        (__attribute__((address_space(3))) uint32_t*)l, 16, 0, 0);
}

// ---------------- f32 -> bf16 hi + bf16 lo (split) ----------------
__global__ __launch_bounds__(256) void conv_split(const float* __restrict__ in,
                                                  bf16* __restrict__ hi,
                                                  bf16* __restrict__ lo) {
    int i = (blockIdx.x * 256 + threadIdx.x) * 4;
    float4 v = *(const float4*)(in + i);
    bf16x4 h, l;
    h.x = (bf16)v.x; l.x = (bf16)(v.x - (float)h.x);
    h.y = (bf16)v.y; l.y = (bf16)(v.y - (float)h.y);
    h.z = (bf16)v.z; l.z = (bf16)(v.z - (float)h.z);
    h.w = (bf16)v.w; l.w = (bf16)(v.w - (float)h.w);
    *(bf16x4*)(hi + i) = h;
    *(bf16x4*)(lo + i) = l;
}

// ---------------- transpose + split: W[K][N] f32 -> WT[N][K] bf16 hi/lo ----------------
__global__ __launch_bounds__(256) void trans_split(const float* __restrict__ W,
                                                   bf16* __restrict__ WThi,
                                                   bf16* __restrict__ WTlo,
                                                   int K, int N) {
    __shared__ float s[32][33];
    int nt = blockIdx.x, kt = blockIdx.y;
    int tx = threadIdx.x & 31, ty = threadIdx.x >> 5;   // 32 x 8
#pragma unroll
    for (int i = 0; i < 4; i++) {
        int k = kt * 32 + ty + i * 8;
        int n = nt * 32 + tx;
        s[tx][ty + i * 8] = W[(long)k * N + n];         // s[n_local][k_local]
    }
    __syncthreads();
#pragma unroll
    for (int i = 0; i < 4; i++) {
        int n = nt * 32 + ty + i * 8;
        int k = kt * 32 + tx;
        float v = s[ty + i * 8][tx];
        bf16 h = (bf16)v;
        WThi[(long)n * K + k] = h;
        WTlo[(long)n * K + k] = (bf16)(v - (float)h);
    }
}

// ---------------- low-rank first factors: t_gk = X@Wgk1, t_g = X@Wg1 ([4096][16]) ----------------
__global__ __launch_bounds__(256) void lowrank1(const float* __restrict__ X,
                                                const float* __restrict__ Wgk1,
                                                const float* __restrict__ Wg1,
                                                float* __restrict__ t_gk,
                                                float* __restrict__ t_g) {
    __shared__ float red[32][9];
    int r = blockIdx.x;
    int out = threadIdx.x & 31, part = threadIdx.x >> 5;
    int col = out & 15;
    const float* W = (out < 16) ? Wgk1 : Wg1;
    const float* xr = X + (long)r * Dq;
    float s = 0.f;
    for (int kk = part; kk < Dq; kk += 8)
        s += xr[kk] * W[kk * 16 + col];
    red[out][part] = s;
    __syncthreads();
    if (threadIdx.x < 32) {
        float t = 0.f;
#pragma unroll
        for (int p = 0; p < 8; p++) t += red[threadIdx.x][p];
        if (threadIdx.x < 16) t_gk[r * 16 + col] = t;
        else                  t_g [r * 16 + col] = t;
    }
}

// ---------------- gk = logsigmoid(t_gk@Wgk2 + bgk2)/16  ([4096][1024] f32) ----------------
__global__ __launch_bounds__(256) void gk_expand(const float* __restrict__ t_gk,
                                                 const float* __restrict__ Wgk2,
                                                 const float* __restrict__ bgk2,
                                                 float* __restrict__ gkout) {
    int r = blockIdx.x;
    float t[16];
#pragma unroll
    for (int rr = 0; rr < 16; rr++) t[rr] = t_gk[r * 16 + rr];
#pragma unroll
    for (int i = 0; i < 4; i++) {
        int col = threadIdx.x + i * 256;
        float z = bgk2[col];
#pragma unroll
        for (int rr = 0; rr < 16; rr++) z += t[rr] * Wgk2[rr * 1024 + col];
        float ls = fminf(z, 0.f) - log1pf(__expf(-fabsf(z)));
        gkout[(long)r * 1024 + col] = ls * 0.0625f;
    }
}

// ---------------- split-3 GEMM: C = (Ahi+Alo)(Bhi+Blo)^T approx, epilogue modes ----------------
// phases: AhiBhi + AloBhi + AhiBlo.  mode 0: none; 1: silu; 2: silu * DK^-0.5
__global__ __launch_bounds__(256) void gemm_bt3(const bf16* __restrict__ Ahi,
                                                const bf16* __restrict__ Alo,
                                                const bf16* __restrict__ Bhi,
                                                const bf16* __restrict__ Blo,
                                                float* __restrict__ C,
                                                int N, int mode) {
    const int K = 2048;
    __shared__ __align__(16) bf16 sA[128 * 32];
    __shared__ __align__(16) bf16 sB[128 * 32];
    int tid = threadIdx.x;
    int wave = tid >> 6, lane = tid & 63;
    int quad = lane >> 4, l16 = lane & 15;
    int bm = blockIdx.x & 31;          // M/128 = 32 tiles
    int bn = blockIdx.x >> 5;
    int wm = (wave >> 1) * 64, wn = (wave & 1) * 64;

    const int c0 = tid, c1 = tid + 256;
    const int ar0 = c0 >> 2, ak0 = (c0 & 3) * 8;
    const int ar1 = c1 >> 2, ak1 = (c1 & 3) * 8;

    f32x4 acc[4][4] = {};

#pragma unroll
    for (int ph = 0; ph < 3; ph++) {
        const bf16* Ap = (ph == 1) ? Alo : Ahi;
        const bf16* Bp = (ph == 2) ? Blo : Bhi;
        const bf16* Ab = Ap + (long)(bm * 128) * K;
        const bf16* Bb = Bp + (long)(bn * 128) * K;
        for (int k0 = 0; k0 < K; k0 += 32) {
            gl_lds16(Ab + (long)ar0 * K + k0 + ak0, sA + c0 * 8);
            gl_lds16(Ab + (long)ar1 * K + k0 + ak1, sA + c1 * 8);
            gl_lds16(Bb + (long)ar0 * K + k0 + ak0, sB + c0 * 8);
            gl_lds16(Bb + (long)ar1 * K + k0 + ak1, sB + c1 * 8);
            __syncthreads();
            bf16x8 af[4], bfr[4];
#pragma unroll
            for (int i = 0; i < 4; i++)
                af[i] = *(const bf16x8*)(sA + (wm + i * 16 + l16) * 32 + quad * 8);
#pragma unroll
            for (int j = 0; j < 4; j++)
                bfr[j] = *(const bf16x8*)(sB + (wn + j * 16 + l16) * 32 + quad * 8);
#pragma unroll
            for (int i = 0; i < 4; i++)
#pragma unroll
                for (int j = 0; j < 4; j++)
                    acc[i][j] = __builtin_amdgcn_mfma_f32_16x16x32_bf16(af[i], bfr[j], acc[i][j], 0, 0, 0);
            __syncthreads();
        }
    }
#pragma unroll
    for (int i = 0; i < 4; i++)
#pragma unroll
        for (int j = 0; j < 4; j++) {
            int row0 = bm * 128 + wm + i * 16 + quad * 4;
            int col  = bn * 128 + wn + j * 16 + l16;
#pragma unroll
            for (int r = 0; r < 4; r++) {
                float x = acc[i][j][r];
                if (mode >= 1) x = x / (1.f + __expf(-x));
                if (mode == 2) x *= 0.125f;          // DK^-0.5
                C[(long)(row0 + r) * N + col] = x;
            }
        }
}

// ---------------- GLA pass 1: per-chunk U, decay ----------------
#define ST 76
__global__ __launch_bounds__(256) void gla_pass1(const float* __restrict__ kbuf,
                                                 const float* __restrict__ vbuf,
                                                 const float* __restrict__ gkb,
                                                 float* __restrict__ U,
                                                 float* __restrict__ dec) {
    __shared__ float sG[64 * ST];
    __shared__ float sK[64 * ST];
    int blk = blockIdx.x;                       // (b*16+h)*32 + c
    int c = blk & 31, h = (blk >> 5) & 15, b = blk >> 9;
    int tid = threadIdx.x;
    long rowbase = (long)b * Tq + c * 64;
#pragma unroll
    for (int i = 0; i < 16; i++) {
        int idx = tid + i * 256;
        int t = idx >> 6, d = idx & 63;
        sG[t * ST + d] = gkb[(rowbase + t) * 1024 + h * 64 + d];
    }
    __syncthreads();
    if (tid < 64) {
        float run = 0.f;
        for (int t = 0; t < 64; t++) { run += sG[t * ST + tid]; sG[t * ST + tid] = run; }
        dec[blk * 64 + tid] = __expf(run);
    }
    __syncthreads();
#pragma unroll
    for (int i = 0; i < 16; i++) {
        int idx = tid + i * 256;
        int t = idx >> 6, d = idx & 63;
        float gl = sG[63 * ST + d];
        sK[t * ST + d] = kbuf[(rowbase + t) * 1024 + h * 64 + d] * __expf(gl - sG[t * ST + d]);
    }
    __syncthreads();
    // U[d][e] = sum_t sK[t][d] * v[t][e];  thread (ty,tx): d rows ty*4.., e cols tx*8..
    int ty = tid >> 4, tx = tid & 15;
    float acc[4][8] = {};
    const float* vb = vbuf + rowbase * 2048 + h * 128 + tx * 8;
    for (int t = 0; t < 64; t++) {
        float4 v0 = *(const float4*)(vb + (long)t * 2048);
        float4 v1 = *(const float4*)(vb + (long)t * 2048 + 4);
        float ve[8] = {v0.x, v0.y, v0.z, v0.w, v1.x, v1.y, v1.z, v1.w};
#pragma unroll
        for (int r = 0; r < 4; r++) {
            float kd = sK[t * ST + ty * 4 + r];
#pragma unroll
            for (int e = 0; e < 8; e++) acc[r][e] += kd * ve[e];
        }
    }
    float* Ub = U + (long)blk * 8192 + (ty * 4) * 128 + tx * 8;
#pragma unroll
    for (int r = 0; r < 4; r++) {
        float4 o0 = {acc[r][0], acc[r][1], acc[r][2], acc[r][3]};
        float4 o1 = {acc[r][4], acc[r][5], acc[r][6], acc[r][7]};
        *(float4*)(Ub + r * 128)     = o0;
        *(float4*)(Ub + r * 128 + 4) = o1;
    }
}

// ---------------- GLA pass 2: scan over chunks (in-place U -> S_prev) ----------------
__global__ __launch_bounds__(256) void gla_pass2(float* __restrict__ U,
                                                 const float* __restrict__ dec) {
    int bh = blockIdx.x >> 5;
    int base = (blockIdx.x & 31) * 256 + threadIdx.x;   // 0..8191
    int d = base >> 7;
    float S = 0.f;
    long off = (long)bh * NCq * 8192 + base;
    for (int c = 0; c < NCq; c++) {
        float u = U[off + (long)c * 8192];
        float dc = dec[(bh * NCq + c) * 64 + d];
        U[off + (long)c * 8192] = S;       // state BEFORE chunk c
        S = S * dc + u;
    }
}

// ---------------- GLA pass 3: o = qg@S_prev + tril(qg kg^T)@v  (writes o over v) ----------------
__global__ __launch_bounds__(256) void gla_pass3(const float* __restrict__ qbuf,
                                                 const float* __restrict__ kbuf,
                                                 float* __restrict__ vbuf,
                                                 const float* __restrict__ gkb,
                                                 const float* __restrict__ Sbuf) {
    __shared__ float sQ[64 * ST];
    __shared__ float sK[64 * ST];
    __shared__ float sA[64 * ST];   // G, then A
    int blk = blockIdx.x;
    int c = blk & 31, h = (blk >> 5) & 15, b = blk >> 9;
    int tid = threadIdx.x;
    long rowbase = (long)b * Tq + c * 64;
#pragma unroll
    for (int i = 0; i < 16; i++) {
        int idx = tid + i * 256;
        int t = idx >> 6, d = idx & 63;
        sA[t * ST + d] = gkb[(rowbase + t) * 1024 + h * 64 + d];
    }
    __syncthreads();
    if (tid < 64) {
        float run = 0.f;
        for (int t = 0; t < 64; t++) { run += sA[t * ST + tid]; sA[t * ST + tid] = run; }
    }
    __syncthreads();
#pragma unroll
    for (int i = 0; i < 16; i++) {
        int idx = tid + i * 256;
        int t = idx >> 6, d = idx & 63;
        float G = sA[t * ST + d];
        long g = (rowbase + t) * 1024 + h * 64 + d;
        sQ[t * ST + d] = qbuf[g] * __expf(G);
        sK[t * ST + d] = kbuf[g] * __expf(-G);
    }
    __syncthreads();
    int ty = tid >> 4, tx = tid & 15;
    // A = tril(sQ sK^T): thread computes rows ty*4..+3, cols tx*4..+3
    {
        float a[4][4] = {};
        for (int d4 = 0; d4 < 16; d4++) {
            float4 qv[4], kv[4];
#pragma unroll
            for (int r = 0; r < 4; r++) qv[r] = *(const float4*)&sQ[(ty * 4 + r) * ST + d4 * 4];
#pragma unroll
            for (int cc = 0; cc < 4; cc++) kv[cc] = *(const float4*)&sK[(tx * 4 + cc) * ST + d4 * 4];
#pragma unroll
            for (int r = 0; r < 4; r++)
#pragma unroll
                for (int cc = 0; cc < 4; cc++)
                    a[r][cc] += qv[r].x * kv[cc].x + qv[r].y * kv[cc].y +
                                qv[r].z * kv[cc].z + qv[r].w * kv[cc].w;
        }
#pragma unroll
        for (int r = 0; r < 4; r++) {
            int ii = ty * 4 + r;
            float4 row;
            row.x = (tx * 4 + 0 <= ii) ? a[r][0] : 0.f;
            row.y = (tx * 4 + 1 <= ii) ? a[r][1] : 0.f;
            row.z = (tx * 4 + 2 <= ii) ? a[r][2] : 0.f;
            row.w = (tx * 4 + 3 <= ii) ? a[r][3] : 0.f;
            *(float4*)&sA[ii * ST + tx * 4] = row;
        }
    }
    __syncthreads();
    // o: thread (ty,tx): rows ty*4..+3, cols tx*8..+7
    float acc[4][8] = {};
    const float* Sb = Sbuf + (long)blk * 8192 + tx * 8;
    for (int d = 0; d < 64; d++) {
        float4 s0 = *(const float4*)(Sb + d * 128);
        float4 s1 = *(const float4*)(Sb + d * 128 + 4);
        float se[8] = {s0.x, s0.y, s0.z, s0.w, s1.x, s1.y, s1.z, s1.w};
#pragma unroll
        for (int r = 0; r < 4; r++) {
            float qv = sQ[(ty * 4 + r) * ST + d];
#pragma unroll
            for (int e = 0; e < 8; e++) acc[r][e] += qv * se[e];
        }
    }
    float* vb = vbuf + rowbase * 2048 + h * 128 + tx * 8;
    for (int j = 0; j < ty * 4 + 4; j++) {
        float4 v0 = *(const float4*)(vb + (long)j * 2048);
        float4 v1 = *(const float4*)(vb + (long)j * 2048 + 4);
        float ve[8] = {v0.x, v0.y, v0.z, v0.w, v1.x, v1.y, v1.z, v1.w};
#pragma unroll
        for (int r = 0; r < 4; r++) {
            float av = sA[(ty * 4 + r) * ST + j];
#pragma unroll
            for (int e = 0; e < 8; e++) acc[r][e] += av * ve[e];
        }
    }
    __syncthreads();   // all v reads done before overwrite
#pragma unroll
    for (int r = 0; r < 4; r++) {
        float4 o0 = {acc[r][0], acc[r][1], acc[r][2], acc[r][3]};
        float4 o1 = {acc[r][4], acc[r][5], acc[r][6], acc[r][7]};
        *(float4*)(vb + (long)(ty * 4 + r) * 2048)     = o0;
        *(float4*)(vb + (long)(ty * 4 + r) * 2048 + 4) = o1;
    }
}

// ---------------- pass 4: RMS-norm over DV, * gnorm_w, * sigmoid(g), emit bf16 hi/lo ----------------
__global__ __launch_bounds__(256) void norm_gate(const float* __restrict__ o,
                                                 const float* __restrict__ t_g,
                                                 const float* __restrict__ Wg2,
                                                 const float* __restrict__ bg2,
                                                 const float* __restrict__ gnw,
                                                 bf16* __restrict__ Ohi,
                                                 bf16* __restrict__ Olo) {
    int w = threadIdx.x >> 6, lane = threadIdx.x & 63;
    int gidx = blockIdx.x * 4 + w;       // (b*T + t)*H + h
    int r = gidx >> 4, h = gidx & 15;
    int e0 = lane * 2;
    long base = (long)r * 2048 + h * 128 + e0;
    float x0 = o[base], x1 = o[base + 1];
    float ss = x0 * x0 + x1 * x1;
#pragma unroll
    for (int off = 1; off < 64; off <<= 1) ss += __shfl_xor(ss, off);
    float scale = rsqrtf(ss * (1.f / 128.f) + 1e-5f);
    int col = h * 128 + e0;
    float g0 = bg2[col], g1 = bg2[col + 1];
#pragma unroll
    for (int rr = 0; rr < 16; rr++) {
        float t = t_g[r * 16 + rr];
        g0 += t * Wg2[rr * 2048 + col];
        g1 += t * Wg2[rr * 2048 + col + 1];
    }
    float y0 = x0 * scale * gnw[e0]     / (1.f + __expf(-g0));
    float y1 = x1 * scale * gnw[e0 + 1] / (1.f + __expf(-g1));
    bf16 h0 = (bf16)y0, h1 = (bf16)y1;
    Ohi[base]     = h0;
    Ohi[base + 1] = h1;
    Olo[base]     = (bf16)(y0 - (float)h0);
    Olo[base + 1] = (bf16)(y1 - (float)h1);
}

extern "C" void kernel_launch(void* const* d_in, const int* in_sizes, int n_in,
                              void* d_out, int out_size, void* d_ws, size_t ws_size,
                              hipStream_t stream) {
    const float* hs   = (const float*)d_in[0];
    const float* Wq   = (const float*)d_in[1];
    const float* Wk   = (const float*)d_in[2];
    const float* Wv   = (const float*)d_in[3];
    const float* Wgk1 = (const float*)d_in[4];
    const float* Wgk2 = (const float*)d_in[5];
    const float* bgk2 = (const float*)d_in[6];
    const float* Wg1  = (const float*)d_in[7];
    const float* Wg2  = (const float*)d_in[8];
    const float* bg2  = (const float*)d_in[9];
    const float* Wo   = (const float*)d_in[10];
    const float* gnw  = (const float*)d_in[11];

    char* w = (char*)d_ws;
    auto alloc = [&](size_t bytes) {
        char* p = w; w += (bytes + 255) & ~size_t(255); return (void*)p;
    };
    bf16*  Xhi   = (bf16*) alloc((size_t)Mq * Dq * 2);       // 16 MB (reused for Ohi)
    bf16*  Xlo   = (bf16*) alloc((size_t)Mq * Dq * 2);       // 16 MB (reused for Olo)
    bf16*  WqThi = (bf16*) alloc((size_t)1024 * 2048 * 2);
    bf16*  WqTlo = (bf16*) alloc((size_t)1024 * 2048 * 2);
    bf16*  WkThi = (bf16*) alloc((size_t)1024 * 2048 * 2);
    bf16*  WkTlo = (bf16*) alloc((size_t)1024 * 2048 * 2);
    bf16*  WvThi = (bf16*) alloc((size_t)2048 * 2048 * 2);
    bf16*  WvTlo = (bf16*) alloc((size_t)2048 * 2048 * 2);
    bf16*  WoThi = (bf16*) alloc((size_t)2048 * 2048 * 2);
    bf16*  WoTlo = (bf16*) alloc((size_t)2048 * 2048 * 2);
    float* qb    = (float*)alloc((size_t)Mq * 1024 * 4);     // 16 MB
    float* kb    = (float*)alloc((size_t)Mq * 1024 * 4);     // 16 MB
    float* vb    = (float*)alloc((size_t)Mq * 2048 * 4);     // 32 MB (o written in-place)
    float* gkb   = (float*)alloc((size_t)Mq * 1024 * 4);     // 16 MB
    float* t_gk  = (float*)alloc((size_t)Mq * 16 * 4);
    float* t_g   = (float*)alloc((size_t)Mq * 16 * 4);
    float* U     = (float*)alloc((size_t)NBH * NCq * 8192 * 4); // 33.5 MB (Sbuf in-place)
    float* dec   = (float*)alloc((size_t)NBH * NCq * 64 * 4);

    conv_split<<<Mq * Dq / 1024, 256, 0, stream>>>(hs, Xhi, Xlo);
    trans_split<<<dim3(1024 / 32, 2048 / 32), 256, 0, stream>>>(Wq, WqThi, WqTlo, 2048, 1024);
    trans_split<<<dim3(1024 / 32, 2048 / 32), 256, 0, stream>>>(Wk, WkThi, WkTlo, 2048, 1024);
    trans_split<<<dim3(2048 / 32, 2048 / 32), 256, 0, stream>>>(Wv, WvThi, WvTlo, 2048, 2048);
    trans_split<<<dim3(2048 / 32, 2048 / 32), 256, 0, stream>>>(Wo, WoThi, WoTlo, 2048, 2048);
    lowrank1<<<Mq, 256, 0, stream>>>(hs, Wgk1, Wg1, t_gk, t_g);
    gk_expand<<<Mq, 256, 0, stream>>>(t_gk, Wgk2, bgk2, gkb);

    gemm_bt3<<<32 * 8,  256, 0, stream>>>(Xhi, Xlo, WqThi, WqTlo, qb, 1024, 2);  // silu * DK^-0.5
    gemm_bt3<<<32 * 8,  256, 0, stream>>>(Xhi, Xlo, WkThi, WkTlo, kb, 1024, 1);  // silu
    gemm_bt3<<<32 * 16, 256, 0, stream>>>(Xhi, Xlo, WvThi, WvTlo, vb, 2048, 1);  // silu

    gla_pass1<<<NBH * NCq, 256, 0, stream>>>(kb, vb, gkb, U, dec);
    gla_pass2<<<NBH * NCq, 256, 0, stream>>>(U, dec);
    gla_pass3<<<NBH * NCq, 256, 0, stream>>>(qb, kb, vb, gkb, U);

    // Ohi/Olo reuse Xhi/Xlo space (X no longer needed after v GEMM)
    norm_gate<<<Mq * Hq / 4, 256, 0, stream>>>(vb, t_g, Wg2, bg2, gnw, Xhi, Xlo);

    gemm_bt3<<<32 * 16, 256, 0, stream>>>(Xhi, Xlo, WoThi, WoTlo, (float*)d_out, 2048, 0);
}

// Round 3
// 730.248 us; speedup vs baseline: 1.3227x; 1.3227x over previous
//
#include <hip/hip_runtime.h>
#include <cstdint>

// Problem constants
#define Bq   2
#define Tq   2048
#define Dq   2048
#define Hq   16
#define DKq  64
#define DVq  128
#define Cq   64          // chunk len
#define NCq  32          // chunks
#define Mq   4096        // B*T
#define NBH  32          // B*H

typedef __bf16 bf16;
typedef __bf16 bf16x4 __attribute__((ext_vector_type(4)));
typedef __bf16 bf16x8 __attribute__((ext_vector_type(8)));
typedef float  f32x4  __attribute__((ext_vector_type(4)));

__device__ __forceinline__ void gl_lds16(const bf16* g, bf16* l) {
    __builtin_amdgcn_global_load_lds(
        (const __attribute__((address_space(1))) uint32_t*)g,
        (__attribute__((address_space(3))) uint32_t*)l, 16, 0, 0);
}

// ---------------- f32 -> bf16 hi + bf16 lo (split) ----------------
__global__ __launch_bounds__(256) void conv_split(const float* __restrict__ in,
                                                  bf16* __restrict__ hi,
                                                  bf16* __restrict__ lo) {
    int i = (blockIdx.x * 256 + threadIdx.x) * 4;
    float4 v = *(const float4*)(in + i);
    bf16x4 h, l;
    h.x = (bf16)v.x; l.x = (bf16)(v.x - (float)h.x);
    h.y = (bf16)v.y; l.y = (bf16)(v.y - (float)h.y);
    h.z = (bf16)v.z; l.z = (bf16)(v.z - (float)h.z);
    h.w = (bf16)v.w; l.w = (bf16)(v.w - (float)h.w);
    *(bf16x4*)(hi + i) = h;
    *(bf16x4*)(lo + i) = l;
}

// ---------------- transpose + split: W[K][N] f32 -> WT[N][K] bf16 hi/lo ----------------
__global__ __launch_bounds__(256) void trans_split(const float* __restrict__ W,
                                                   bf16* __restrict__ WThi,
                                                   bf16* __restrict__ WTlo,
                                                   int K, int N) {
    __shared__ float s[32][33];
    int nt = blockIdx.x, kt = blockIdx.y;
    int tx = threadIdx.x & 31, ty = threadIdx.x >> 5;   // 32 x 8
#pragma unroll
    for (int i = 0; i < 4; i++) {
        int k = kt * 32 + ty + i * 8;
        int n = nt * 32 + tx;
        s[tx][ty + i * 8] = W[(long)k * N + n];         // s[n_local][k_local]
    }
    __syncthreads();
#pragma unroll
    for (int i = 0; i < 4; i++) {
        int n = nt * 32 + ty + i * 8;
        int k = kt * 32 + tx;
        float v = s[ty + i * 8][tx];
        bf16 h = (bf16)v;
        WThi[(long)n * K + k] = h;
        WTlo[(long)n * K + k] = (bf16)(v - (float)h);
    }
}

// ---------------- low-rank first factors (LDS-staged, coalesced) ----------------
__global__ __launch_bounds__(256) void lowrank1(const float* __restrict__ X,
                                                const float* __restrict__ Wgk1,
                                                const float* __restrict__ Wg1,
                                                float* __restrict__ t_gk,
                                                float* __restrict__ t_g) {
    __shared__ float sx[2048];
    __shared__ float red[32][9];
    int r = blockIdx.x;
    const float* xr = X + (long)r * Dq;
#pragma unroll
    for (int i = 0; i < 2; i++) {
        int idx = (threadIdx.x + i * 256) * 4;
        *(float4*)&sx[idx] = *(const float4*)(xr + idx);
    }
    __syncthreads();
    int out = threadIdx.x & 31, part = threadIdx.x >> 5;
    int col = out & 15;
    const float* W = (out < 16) ? Wgk1 : Wg1;
    float s = 0.f;
    for (int kk = part; kk < Dq; kk += 8)
        s += sx[kk] * W[kk * 16 + col];
    red[out][part] = s;
    __syncthreads();
    if (threadIdx.x < 32) {
        float t = 0.f;
#pragma unroll
        for (int p = 0; p < 8; p++) t += red[threadIdx.x][p];
        int c = threadIdx.x & 15;
        if (threadIdx.x < 16) t_gk[r * 16 + c] = t;
        else                  t_g [r * 16 + c] = t;
    }
}

// ---------------- gk = logsigmoid(t_gk@Wgk2 + bgk2)/16  ([4096][1024] f32) ----------------
__global__ __launch_bounds__(256) void gk_expand(const float* __restrict__ t_gk,
                                                 const float* __restrict__ Wgk2,
                                                 const float* __restrict__ bgk2,
                                                 float* __restrict__ gkout) {
    int r = blockIdx.x;
    float t[16];
#pragma unroll
    for (int rr = 0; rr < 16; rr++) t[rr] = t_gk[r * 16 + rr];
#pragma unroll
    for (int i = 0; i < 4; i++) {
        int col = threadIdx.x + i * 256;
        float z = bgk2[col];
#pragma unroll
        for (int rr = 0; rr < 16; rr++) z += t[rr] * Wgk2[rr * 1024 + col];
        float ls = fminf(z, 0.f) - log1pf(__expf(-fabsf(z)));
        gkout[(long)r * 1024 + col] = ls * 0.0625f;
    }
}

// ---------------- split-3 GEMM, 4-buffer single K-loop ----------------
// acc = AhiBhi + AloBhi + AhiBlo (48 MFMA per barrier).
// mode 0: plain write to o0 [M][Ncols]; mode 1: qkv routing with silu (+0.125 for q cols)
__global__ __launch_bounds__(256, 2) void gemm3(const bf16* __restrict__ Ahi,
                                                const bf16* __restrict__ Alo,
                                                const bf16* __restrict__ Bhi,
                                                const bf16* __restrict__ Blo,
                                                float* __restrict__ o0,
                                                float* __restrict__ o1,
                                                float* __restrict__ o2,
                                                int Ncols, int mode) {
    const int K = 2048;
    __shared__ __align__(16) bf16 sAh[128 * 32];
    __shared__ __align__(16) bf16 sAl[128 * 32];
    __shared__ __align__(16) bf16 sBh[128 * 32];
    __shared__ __align__(16) bf16 sBl[128 * 32];
    int tid = threadIdx.x;
    int wave = tid >> 6, lane = tid & 63;
    int quad = lane >> 4, l16 = lane & 15;
    int bm = blockIdx.x & 31;
    int bn = blockIdx.x >> 5;
    int wm = (wave >> 1) * 64, wn = (wave & 1) * 64;

    const int c0 = tid, c1 = tid + 256;
    const int ar0 = c0 >> 2, ak0 = (c0 & 3) * 8;
    const int ar1 = c1 >> 2, ak1 = (c1 & 3) * 8;
    const bf16* Ah = Ahi + (long)(bm * 128) * K;
    const bf16* Al = Alo + (long)(bm * 128) * K;
    const bf16* Bh = Bhi + (long)(bn * 128) * K;
    const bf16* Bl = Blo + (long)(bn * 128) * K;

    f32x4 acc[4][4] = {};

    for (int k0 = 0; k0 < K; k0 += 32) {
        gl_lds16(Ah + (long)ar0 * K + k0 + ak0, sAh + c0 * 8);
        gl_lds16(Ah + (long)ar1 * K + k0 + ak1, sAh + c1 * 8);
        gl_lds16(Al + (long)ar0 * K + k0 + ak0, sAl + c0 * 8);
        gl_lds16(Al + (long)ar1 * K + k0 + ak1, sAl + c1 * 8);
        gl_lds16(Bh + (long)ar0 * K + k0 + ak0, sBh + c0 * 8);
        gl_lds16(Bh + (long)ar1 * K + k0 + ak1, sBh + c1 * 8);
        gl_lds16(Bl + (long)ar0 * K + k0 + ak0, sBl + c0 * 8);
        gl_lds16(Bl + (long)ar1 * K + k0 + ak1, sBl + c1 * 8);
        __syncthreads();
        bf16x8 ah[4], bh[4], xf[4];
#pragma unroll
        for (int i = 0; i < 4; i++)
            ah[i] = *(const bf16x8*)(sAh + (wm + i * 16 + l16) * 32 + quad * 8);
#pragma unroll
        for (int j = 0; j < 4; j++)
            bh[j] = *(const bf16x8*)(sBh + (wn + j * 16 + l16) * 32 + quad * 8);
#pragma unroll
        for (int i = 0; i < 4; i++)
#pragma unroll
            for (int j = 0; j < 4; j++)
                acc[i][j] = __builtin_amdgcn_mfma_f32_16x16x32_bf16(ah[i], bh[j], acc[i][j], 0, 0, 0);
#pragma unroll
        for (int i = 0; i < 4; i++)
            xf[i] = *(const bf16x8*)(sAl + (wm + i * 16 + l16) * 32 + quad * 8);
#pragma unroll
        for (int i = 0; i < 4; i++)
#pragma unroll
            for (int j = 0; j < 4; j++)
                acc[i][j] = __builtin_amdgcn_mfma_f32_16x16x32_bf16(xf[i], bh[j], acc[i][j], 0, 0, 0);
#pragma unroll
        for (int j = 0; j < 4; j++)
            xf[j] = *(const bf16x8*)(sBl + (wn + j * 16 + l16) * 32 + quad * 8);
#pragma unroll
        for (int i = 0; i < 4; i++)
#pragma unroll
            for (int j = 0; j < 4; j++)
                acc[i][j] = __builtin_amdgcn_mfma_f32_16x16x32_bf16(ah[i], xf[j], acc[i][j], 0, 0, 0);
        __syncthreads();
    }
#pragma unroll
    for (int i = 0; i < 4; i++)
#pragma unroll
        for (int j = 0; j < 4; j++) {
            int row0 = bm * 128 + wm + i * 16 + quad * 4;
            int col  = bn * 128 + wn + j * 16 + l16;
            if (mode == 0) {
#pragma unroll
                for (int r = 0; r < 4; r++)
                    o0[(long)(row0 + r) * Ncols + col] = acc[i][j][r];
            } else {
                float scale = (col < 1024) ? 0.125f : 1.0f;
                float* dst; int cw, cc;
                if (col < 1024)      { dst = o0; cw = 1024; cc = col; }
                else if (col < 2048) { dst = o1; cw = 1024; cc = col - 1024; }
                else                 { dst = o2; cw = 2048; cc = col - 2048; }
#pragma unroll
                for (int r = 0; r < 4; r++) {
                    float x = acc[i][j][r];
                    x = x / (1.f + __expf(-x)) * scale;
                    dst[(long)(row0 + r) * cw + cc] = x;
                }
            }
        }
}

// ---------------- GLA pass 1: per-chunk U, decay ----------------
#define ST 76
__global__ __launch_bounds__(256) void gla_pass1(const float* __restrict__ kbuf,
                                                 const float* __restrict__ vbuf,
                                                 const float* __restrict__ gkb,
                                                 float* __restrict__ U,
                                                 float* __restrict__ dec) {
    __shared__ float sG[64 * ST];
    __shared__ float sK[64 * ST];
    int blk = blockIdx.x;                       // (b*16+h)*32 + c
    int c = blk & 31, h = (blk >> 5) & 15, b = blk >> 9;
    int tid = threadIdx.x;
    long rowbase = (long)b * Tq + c * 64;
#pragma unroll
    for (int i = 0; i < 16; i++) {
        int idx = tid + i * 256;
        int t = idx >> 6, d = idx & 63;
        sG[t * ST + d] = gkb[(rowbase + t) * 1024 + h * 64 + d];
    }
    __syncthreads();
    if (tid < 64) {
        float run = 0.f;
        for (int t = 0; t < 64; t++) { run += sG[t * ST + tid]; sG[t * ST + tid] = run; }
        dec[blk * 64 + tid] = __expf(run);
    }
    __syncthreads();
#pragma unroll
    for (int i = 0; i < 16; i++) {
        int idx = tid + i * 256;
        int t = idx >> 6, d = idx & 63;
        float gl = sG[63 * ST + d];
        sK[t * ST + d] = kbuf[(rowbase + t) * 1024 + h * 64 + d] * __expf(gl - sG[t * ST + d]);
    }
    __syncthreads();
    int ty = tid >> 4, tx = tid & 15;
    float acc[4][8] = {};
    const float* vb = vbuf + rowbase * 2048 + h * 128 + tx * 8;
    for (int t = 0; t < 64; t++) {
        float4 v0 = *(const float4*)(vb + (long)t * 2048);
        float4 v1 = *(const float4*)(vb + (long)t * 2048 + 4);
        float ve[8] = {v0.x, v0.y, v0.z, v0.w, v1.x, v1.y, v1.z, v1.w};
#pragma unroll
        for (int r = 0; r < 4; r++) {
            float kd = sK[t * ST + ty * 4 + r];
#pragma unroll
            for (int e = 0; e < 8; e++) acc[r][e] += kd * ve[e];
        }
    }
    float* Ub = U + (long)blk * 8192 + (ty * 4) * 128 + tx * 8;
#pragma unroll
    for (int r = 0; r < 4; r++) {
        float4 o0 = {acc[r][0], acc[r][1], acc[r][2], acc[r][3]};
        float4 o1 = {acc[r][4], acc[r][5], acc[r][6], acc[r][7]};
        *(float4*)(Ub + r * 128)     = o0;
        *(float4*)(Ub + r * 128 + 4) = o1;
    }
}

// ---------------- GLA pass 2: scan over chunks (in-place U -> S_prev) ----------------
__global__ __launch_bounds__(256) void gla_pass2(float* __restrict__ U,
                                                 const float* __restrict__ dec) {
    int bh = blockIdx.x >> 5;
    int base = (blockIdx.x & 31) * 256 + threadIdx.x;   // 0..8191
    int d = base >> 7;
    float S = 0.f;
    long off = (long)bh * NCq * 8192 + base;
    for (int c = 0; c < NCq; c++) {
        float u = U[off + (long)c * 8192];
        float dc = dec[(bh * NCq + c) * 64 + d];
        U[off + (long)c * 8192] = S;       // state BEFORE chunk c
        S = S * dc + u;
    }
}

// ---------------- GLA pass 3: o = qg@S_prev + tril(qg kg^T)@v  (writes o over v) ----------------
__global__ __launch_bounds__(256) void gla_pass3(const float* __restrict__ qbuf,
                                                 const float* __restrict__ kbuf,
                                                 float* __restrict__ vbuf,
                                                 const float* __restrict__ gkb,
                                                 const float* __restrict__ Sbuf) {
    __shared__ float sQ[64 * ST];
    __shared__ float sK[64 * ST];
    __shared__ float sA[64 * ST];   // G, then A
    int blk = blockIdx.x;
    int c = blk & 31, h = (blk >> 5) & 15, b = blk >> 9;
    int tid = threadIdx.x;
    long rowbase = (long)b * Tq + c * 64;
#pragma unroll
    for (int i = 0; i < 16; i++) {
        int idx = tid + i * 256;
        int t = idx >> 6, d = idx & 63;
        sA[t * ST + d] = gkb[(rowbase + t) * 1024 + h * 64 + d];
    }
    __syncthreads();
    if (tid < 64) {
        float run = 0.f;
        for (int t = 0; t < 64; t++) { run += sA[t * ST + tid]; sA[t * ST + tid] = run; }
    }
    __syncthreads();
#pragma unroll
    for (int i = 0; i < 16; i++) {
        int idx = tid + i * 256;
        int t = idx >> 6, d = idx & 63;
        float G = sA[t * ST + d];
        long g = (rowbase + t) * 1024 + h * 64 + d;
        sQ[t * ST + d] = qbuf[g] * __expf(G);
        sK[t * ST + d] = kbuf[g] * __expf(-G);
    }
    __syncthreads();
    int ty = tid >> 4, tx = tid & 15;
    {
        float a[4][4] = {};
        for (int d4 = 0; d4 < 16; d4++) {
            float4 qv[4], kv[4];
#pragma unroll
            for (int r = 0; r < 4; r++) qv[r] = *(const float4*)&sQ[(ty * 4 + r) * ST + d4 * 4];
#pragma unroll
            for (int cc = 0; cc < 4; cc++) kv[cc] = *(const float4*)&sK[(tx * 4 + cc) * ST + d4 * 4];
#pragma unroll
            for (int r = 0; r < 4; r++)
#pragma unroll
                for (int cc = 0; cc < 4; cc++)
                    a[r][cc] += qv[r].x * kv[cc].x + qv[r].y * kv[cc].y +
                                qv[r].z * kv[cc].z + qv[r].w * kv[cc].w;
        }
#pragma unroll
        for (int r = 0; r < 4; r++) {
            int ii = ty * 4 + r;
            float4 row;
            row.x = (tx * 4 + 0 <= ii) ? a[r][0] : 0.f;
            row.y = (tx * 4 + 1 <= ii) ? a[r][1] : 0.f;
            row.z = (tx * 4 + 2 <= ii) ? a[r][2] : 0.f;
            row.w = (tx * 4 + 3 <= ii) ? a[r][3] : 0.f;
            *(float4*)&sA[ii * ST + tx * 4] = row;
        }
    }
    __syncthreads();
    float acc[4][8] = {};
    const float* Sb = Sbuf + (long)blk * 8192 + tx * 8;
    for (int d = 0; d < 64; d++) {
        float4 s0 = *(const float4*)(Sb + d * 128);
        float4 s1 = *(const float4*)(Sb + d * 128 + 4);
        float se[8] = {s0.x, s0.y, s0.z, s0.w, s1.x, s1.y, s1.z, s1.w};
#pragma unroll
        for (int r = 0; r < 4; r++) {
            float qv = sQ[(ty * 4 + r) * ST + d];
#pragma unroll
            for (int e = 0; e < 8; e++) acc[r][e] += qv * se[e];
        }
    }
    float* vb = vbuf + rowbase * 2048 + h * 128 + tx * 8;
    for (int j = 0; j < ty * 4 + 4; j++) {
        float4 v0 = *(const float4*)(vb + (long)j * 2048);
        float4 v1 = *(const float4*)(vb + (long)j * 2048 + 4);
        float ve[8] = {v0.x, v0.y, v0.z, v0.w, v1.x, v1.y, v1.z, v1.w};
#pragma unroll
        for (int r = 0; r < 4; r++) {
            float av = sA[(ty * 4 + r) * ST + j];
#pragma unroll
            for (int e = 0; e < 8; e++) acc[r][e] += av * ve[e];
        }
    }
    __syncthreads();   // all v reads done before overwrite
#pragma unroll
    for (int r = 0; r < 4; r++) {
        float4 o0 = {acc[r][0], acc[r][1], acc[r][2], acc[r][3]};
        float4 o1 = {acc[r][4], acc[r][5], acc[r][6], acc[r][7]};
        *(float4*)(vb + (long)(ty * 4 + r) * 2048)     = o0;
        *(float4*)(vb + (long)(ty * 4 + r) * 2048 + 4) = o1;
    }
}

// ---------------- pass 4: RMS-norm over DV, * gnorm_w, * sigmoid(g), emit bf16 hi/lo ----------------
__global__ __launch_bounds__(256) void norm_gate(const float* __restrict__ o,
                                                 const float* __restrict__ t_g,
                                                 const float* __restrict__ Wg2,
                                                 const float* __restrict__ bg2,
                                                 const float* __restrict__ gnw,
                                                 bf16* __restrict__ Ohi,
                                                 bf16* __restrict__ Olo) {
    int w = threadIdx.x >> 6, lane = threadIdx.x & 63;
    int gidx = blockIdx.x * 4 + w;       // (b*T + t)*H + h
    int r = gidx >> 4, h = gidx & 15;
    int e0 = lane * 2;
    long base = (long)r * 2048 + h * 128 + e0;
    float x0 = o[base], x1 = o[base + 1];
    float ss = x0 * x0 + x1 * x1;
#pragma unroll
    for (int off = 1; off < 64; off <<= 1) ss += __shfl_xor(ss, off);
    float scale = rsqrtf(ss * (1.f / 128.f) + 1e-5f);
    int col = h * 128 + e0;
    float g0 = bg2[col], g1 = bg2[col + 1];
#pragma unroll
    for (int rr = 0; rr < 16; rr++) {
        float t = t_g[r * 16 + rr];
        g0 += t * Wg2[rr * 2048 + col];
        g1 += t * Wg2[rr * 2048 + col + 1];
    }
    float y0 = x0 * scale * gnw[e0]     / (1.f + __expf(-g0));
    float y1 = x1 * scale * gnw[e0 + 1] / (1.f + __expf(-g1));
    bf16 h0 = (bf16)y0, h1 = (bf16)y1;
    Ohi[base]     = h0;
    Ohi[base + 1] = h1;
    Olo[base]     = (bf16)(y0 - (float)h0);
    Olo[base + 1] = (bf16)(y1 - (float)h1);
}

extern "C" void kernel_launch(void* const* d_in, const int* in_sizes, int n_in,
                              void* d_out, int out_size, void* d_ws, size_t ws_size,
                              hipStream_t stream) {
    const float* hs   = (const float*)d_in[0];
    const float* Wq   = (const float*)d_in[1];
    const float* Wk   = (const float*)d_in[2];
    const float* Wv   = (const float*)d_in[3];
    const float* Wgk1 = (const float*)d_in[4];
    const float* Wgk2 = (const float*)d_in[5];
    const float* bgk2 = (const float*)d_in[6];
    const float* Wg1  = (const float*)d_in[7];
    const float* Wg2  = (const float*)d_in[8];
    const float* bg2  = (const float*)d_in[9];
    const float* Wo   = (const float*)d_in[10];
    const float* gnw  = (const float*)d_in[11];

    char* w = (char*)d_ws;
    auto alloc = [&](size_t bytes) {
        char* p = w; w += (bytes + 255) & ~size_t(255); return (void*)p;
    };
    bf16*  Xhi    = (bf16*) alloc((size_t)Mq * Dq * 2);        // 16 MB (reused for Ohi)
    bf16*  Xlo    = (bf16*) alloc((size_t)Mq * Dq * 2);        // 16 MB (reused for Olo)
    bf16*  WqkvThi= (bf16*) alloc((size_t)4096 * 2048 * 2);    // 16 MB  [q|k|v] rows
    bf16*  WqkvTlo= (bf16*) alloc((size_t)4096 * 2048 * 2);    // 16 MB
    bf16*  WoThi  = (bf16*) alloc((size_t)2048 * 2048 * 2);    // 8 MB
    bf16*  WoTlo  = (bf16*) alloc((size_t)2048 * 2048 * 2);    // 8 MB
    float* qb     = (float*)alloc((size_t)Mq * 1024 * 4);      // 16 MB
    float* kb     = (float*)alloc((size_t)Mq * 1024 * 4);      // 16 MB
    float* vb     = (float*)alloc((size_t)Mq * 2048 * 4);      // 32 MB (o written in-place)
    float* gkb    = (float*)alloc((size_t)Mq * 1024 * 4);      // 16 MB
    float* t_gk   = (float*)alloc((size_t)Mq * 16 * 4);
    float* t_g    = (float*)alloc((size_t)Mq * 16 * 4);
    float* U      = (float*)alloc((size_t)NBH * NCq * 8192 * 4); // 33.5 MB (Sbuf in-place)
    float* dec    = (float*)alloc((size_t)NBH * NCq * 64 * 4);

    conv_split<<<Mq * Dq / 1024, 256, 0, stream>>>(hs, Xhi, Xlo);
    trans_split<<<dim3(1024 / 32, 2048 / 32), 256, 0, stream>>>(Wq, WqkvThi, WqkvTlo, 2048, 1024);
    trans_split<<<dim3(1024 / 32, 2048 / 32), 256, 0, stream>>>(Wk, WqkvThi + (size_t)1024 * 2048,
                                                                WqkvTlo + (size_t)1024 * 2048, 2048, 1024);
    trans_split<<<dim3(2048 / 32, 2048 / 32), 256, 0, stream>>>(Wv, WqkvThi + (size_t)2048 * 2048,
                                                                WqkvTlo + (size_t)2048 * 2048, 2048, 2048);
    trans_split<<<dim3(2048 / 32, 2048 / 32), 256, 0, stream>>>(Wo, WoThi, WoTlo, 2048, 2048);
    lowrank1<<<Mq, 256, 0, stream>>>(hs, Wgk1, Wg1, t_gk, t_g);
    gk_expand<<<Mq, 256, 0, stream>>>(t_gk, Wgk2, bgk2, gkb);

    // fused q|k|v GEMM: N = 4096, 32x32 = 1024 blocks
    gemm3<<<32 * 32, 256, 0, stream>>>(Xhi, Xlo, WqkvThi, WqkvTlo, qb, kb, vb, 4096, 1);

    gla_pass1<<<NBH * NCq, 256, 0, stream>>>(kb, vb, gkb, U, dec);
    gla_pass2<<<NBH * NCq, 256, 0, stream>>>(U, dec);
    gla_pass3<<<NBH * NCq, 256, 0, stream>>>(qb, kb, vb, gkb, U);

    // Ohi/Olo reuse Xhi/Xlo space (X no longer needed after qkv GEMM)
    norm_gate<<<Mq * Hq / 4, 256, 0, stream>>>(vb, t_g, Wg2, bg2, gnw, Xhi, Xlo);

    // out GEMM: N = 2048, 32x16 = 512 blocks
    gemm3<<<32 * 16, 256, 0, stream>>>(Xhi, Xlo, WoThi, WoTlo, (float*)d_out, nullptr, nullptr, 2048, 0);
}